// Round 6
// baseline (137.899 us; speedup 1.0000x reference)
//
#include <hip/hip_runtime.h>
#include <hip/hip_bf16.h>

typedef __bf16 bf16;
typedef __bf16 bf16x8 __attribute__((ext_vector_type(8)));
typedef float f32x4 __attribute__((ext_vector_type(4)));

#define MFMA_16x16x32(A, B, C) __builtin_amdgcn_mfma_f32_16x16x32_bf16(A, B, C, 0, 0, 0)

static_assert(sizeof(bf16x8) == 16, "bf16x8 must be 16B");

__device__ __forceinline__ bf16x8 cast8(float4 lo, float4 hi) {
  return (bf16x8){(bf16)lo.x, (bf16)lo.y, (bf16)lo.z, (bf16)lo.w,
                  (bf16)hi.x, (bf16)hi.y, (bf16)hi.z, (bf16)hi.w};
}

// ---------------------------------------------------------------------------
// Kernel 0: cast + transpose weights: Wt[p][h][c] = W_p[c][h].
// ---------------------------------------------------------------------------
__global__ __launch_bounds__(256) void wtrans_kernel(
    const float* __restrict__ Wq, const float* __restrict__ Wk,
    const float* __restrict__ Wv, bf16* __restrict__ Wt)
{
  int idx = blockIdx.x * 256 + threadIdx.x;   // 3*64*1024
  int p = idx >> 16;
  int rem = idx & 65535;
  int h = rem >> 10;
  int c = rem & 1023;
  const float* W = (p == 0) ? Wq : (p == 1) ? Wk : Wv;
  Wt[idx] = (bf16)W[c * 64 + h];
}

// ---------------------------------------------------------------------------
// Kernel 1: projections — request-minimal streaming GEMM.
//   bid&1==0 : Q = q @ Wq          bid&1==1 : K = k @ Wk, V = k @ Wv
// BM=128 (4 waves x 32 rows, rf=2), BK=32. A: per-lane register loads in
// MFMA fragment layout, 2-deep named-set prefetch. B: loaded full-line to
// regs, staged in triple-buffered LDS (amortized across the block's 128
// rows — the R1 structure's 60%-request waste eliminated). Loop sync is
// ONE raw s_barrier + lgkmcnt(0) per K-step; NO vmcnt wait anywhere in the
// loop, so prefetch loads stay in flight across barriers (compiler inserts
// counted vmcnt at each consume). No global_load_lds (avoids the DMA-engine
// serialization seen in R2/R3); no __syncthreads (avoids vmcnt(0) drains
// seen in R4/R5).
// ---------------------------------------------------------------------------
__global__ __launch_bounds__(256) void proj_kernel(
    const float* __restrict__ qin, const float* __restrict__ kin,
    const bf16* __restrict__ Wt,
    bf16* __restrict__ Qb, bf16* __restrict__ Kb, bf16* __restrict__ Vtb)
{
  const int bid = blockIdx.x;            // 0..511
  const int p = bid & 1;                 // 0: Q   1: K+V
  const int m0 = (bid >> 1) * 128;
  const float* A = p ? kin : qin;

  __shared__ __align__(16) bf16 Bsh[3][2][64][40];   // 30 KB, 3-buf, +pad

  const int tid = threadIdx.x;
  const int lane = tid & 63;
  const int w = tid >> 6;
  const int g = lane >> 4;
  const int r = lane & 15;
  const int row16 = lane >> 2;           // 0..15  (B staging row)
  const int q4 = lane & 3;               // B staging 16B chunk

  // A fragment pointers: lane (g,r), rf in {a,b}: rows w*32 + rf*16 + r,
  // k-slice f32 idx g*8 (ld1) and g*8+4 (ld2).
  const float* aA = A + (size_t)(m0 + w * 32 + r) * 1024 + g * 8;
  const float* aB = aA + 16 * 1024;

  // B staging pointers: wave w covers Wt rows w*16..w*16+15, full 64B line.
  const bf16* wbase = Wt + (size_t)(w * 16 + row16) * 1024 + q4 * 8;
  const bf16* bp0 = wbase + (size_t)(p ? 1 : 0) * 65536;
  const bf16* bp1 = wbase + (size_t)2 * 65536;

  f32x4 acc[2][2][4];   // [mat][rf][cf]
  #pragma unroll
  for (int mt = 0; mt < 2; mt++)
    #pragma unroll
    for (int rf = 0; rf < 2; rf++)
      #pragma unroll
      for (int cf = 0; cf < 4; cf++)
        acc[mt][rf][cf] = (f32x4){0.f, 0.f, 0.f, 0.f};

  // named register prefetch sets (static indexing — no scratch)
  float4 A1a0, A2a0, A1b0, A2b0, A1a1, A2a1, A1b1, A2b1;
  bf16x8 B00, B10, B01, B11;

#define ISSA(S, K)                                                       \
  do {                                                                   \
    A1a##S = *(const float4*)(aA + (K));                                 \
    A2a##S = *(const float4*)(aA + (K) + 4);                             \
    A1b##S = *(const float4*)(aB + (K));                                 \
    A2b##S = *(const float4*)(aB + (K) + 4);                             \
  } while (0)

#define ISSB(S, K)                                                       \
  do {                                                                   \
    B0##S = *(const bf16x8*)(bp0 + (K));                                 \
    if (p) B1##S = *(const bf16x8*)(bp1 + (K));                          \
  } while (0)

#define WRB(S, BUF)                                                      \
  do {                                                                   \
    *(bf16x8*)&Bsh[BUF][0][w * 16 + row16][q4 * 8] = B0##S;              \
    if (p) *(bf16x8*)&Bsh[BUF][1][w * 16 + row16][q4 * 8] = B1##S;       \
  } while (0)

#define LGKM_BARRIER() \
  asm volatile("s_waitcnt lgkmcnt(0)\n\ts_barrier" ::: "memory")

  auto compute = [&](float4 l1a, float4 l2a, float4 l1b, float4 l2b,
                     int bufR) {
    bf16x8 af0 = cast8(l1a, l2a);
    bf16x8 af1 = cast8(l1b, l2b);
    #pragma unroll
    for (int cf = 0; cf < 4; cf++) {
      bf16x8 b0 = *(const bf16x8*)&Bsh[bufR][0][cf * 16 + r][g * 8];
      acc[0][0][cf] = MFMA_16x16x32(af0, b0, acc[0][0][cf]);
      acc[0][1][cf] = MFMA_16x16x32(af1, b0, acc[0][1][cf]);
    }
    if (p) {
      #pragma unroll
      for (int cf = 0; cf < 4; cf++) {
        bf16x8 b1 = *(const bf16x8*)&Bsh[bufR][1][cf * 16 + r][g * 8];
        acc[1][0][cf] = MFMA_16x16x32(af0, b1, acc[1][0][cf]);
        acc[1][1][cf] = MFMA_16x16x32(af1, b1, acc[1][1][cf]);
      }
    }
  };

  // --- prologue: A(0),A(1),B(0),B(1) issued; B(0) staged; B(2) issued ---
  ISSA(0, 0);  ISSB(0, 0);
  ISSA(1, 32); ISSB(1, 32);
  WRB(0, 0);          // compiler: counted vmcnt for B set0 only
  ISSB(0, 64);        // set0 <- B(2)
  LGKM_BARRIER();

  int bufW = 1, bufR = 0;   // B(t) lives in Bsh[t % 3]
  for (int j = 0; j < 16; ++j) {
    const int t0 = 2 * j, t1 = 2 * j + 1;

    // --- sub-iter t0: A set0 = A(t0); B set1 = B(t0+1) ---
    WRB(1, bufW);                                  // stage B(t0+1)
    if (t0 + 3 < 32) ISSB(1, (t0 + 3) * 32);       // set1 <- B(t0+3)
    LGKM_BARRIER();
    compute(A1a0, A2a0, A1b0, A2b0, bufR);
    if (t0 + 2 < 32) ISSA(0, (t0 + 2) * 32);       // set0 <- A(t0+2)
    bufW = (bufW == 2) ? 0 : bufW + 1;
    bufR = (bufR == 2) ? 0 : bufR + 1;

    // --- sub-iter t1: A set1 = A(t1); B set0 = B(t1+1) ---
    if (t1 + 1 < 32) WRB(0, bufW);                 // stage B(t1+1)
    if (t1 + 3 < 32) ISSB(0, (t1 + 3) * 32);       // set0 <- B(t1+3)
    LGKM_BARRIER();
    compute(A1a1, A2a1, A1b1, A2b1, bufR);
    if (t1 + 2 < 32) ISSA(1, (t1 + 2) * 32);       // set1 <- A(t1+2)
    bufW = (bufW == 2) ? 0 : bufW + 1;
    bufR = (bufR == 2) ? 0 : bufR + 1;
  }

#undef ISSA
#undef ISSB
#undef WRB
#undef LGKM_BARRIER

  // --- epilogue: C/D layout row=(l>>4)*4+j, col=l&15 ---
  #pragma unroll
  for (int rf = 0; rf < 2; rf++) {
    #pragma unroll
    for (int cf = 0; cf < 4; cf++) {
      #pragma unroll
      for (int jj = 0; jj < 4; jj++) {
        int rg = m0 + w * 32 + rf * 16 + g * 4 + jj;
        int col = cf * 16 + r;
        if (p == 0) {
          Qb[(size_t)rg * 64 + col] = (bf16)acc[0][rf][cf][jj];
        } else {
          Kb[(size_t)rg * 64 + col] = (bf16)acc[0][rf][cf][jj];
          int bb = rg >> 11, t2 = rg & 2047;
          Vtb[(size_t)(bb * 64 + col) * 2048 + t2] = (bf16)acc[1][rf][cf][jj];
        }
      }
    }
  }
}

// ---------------------------------------------------------------------------
// Kernel 2: causal flash attention (unchanged).
// ---------------------------------------------------------------------------
__global__ __launch_bounds__(256) void attn_kernel(
    const bf16* __restrict__ Qb, const bf16* __restrict__ Kb,
    const bf16* __restrict__ Vtb, float* __restrict__ out)
{
  const int qt = (int)(gridDim.x - 1 - blockIdx.x);   // heavy blocks first
  const int b = blockIdx.y;
  const int tid = threadIdx.x;
  const int lane = tid & 63;
  const int w = tid >> 6;
  const int g = lane >> 4;
  const int r = lane & 15;

  __shared__ __align__(16) bf16 Ks[64][80];
  __shared__ __align__(16) bf16 Vs[64][80];
  __shared__ __align__(16) bf16 Ps[4][16][80];

  const int q0 = qt * 64 + w * 16;
  const bf16* qp = Qb + (size_t)(b * 2048 + q0 + r) * 64 + g * 8;
  const bf16x8 qf0 = *(const bf16x8*)qp;
  const bf16x8 qf1 = *(const bf16x8*)(qp + 32);

  f32x4 acc_o[4];
  #pragma unroll
  for (int hf = 0; hf < 4; hf++) acc_o[hf] = (f32x4){0.f, 0.f, 0.f, 0.f};
  float m_r[4] = {-1e30f, -1e30f, -1e30f, -1e30f};
  float l_r[4] = {0.f, 0.f, 0.f, 0.f};
  const float scale = 0.03125f;   // 1/sqrt(1024)

  const int sh = tid >> 2;
  const int sc = (tid & 3) * 16;

  for (int kv = 0; kv <= qt; kv++) {
    {
      const bf16* kp = Kb + (size_t)(b * 2048 + kv * 64 + sh) * 64 + sc;
      *(bf16x8*)&Ks[sh][sc]     = *(const bf16x8*)kp;
      *(bf16x8*)&Ks[sh][sc + 8] = *(const bf16x8*)(kp + 8);
      const bf16* vp = Vtb + (size_t)(b * 64 + sh) * 2048 + kv * 64 + sc;
      *(bf16x8*)&Vs[sh][sc]     = *(const bf16x8*)vp;
      *(bf16x8*)&Vs[sh][sc + 8] = *(const bf16x8*)(vp + 8);
    }
    __syncthreads();

    f32x4 s[4];
    #pragma unroll
    for (int cf = 0; cf < 4; cf++) {
      bf16x8 kf0 = *(const bf16x8*)&Ks[cf * 16 + r][g * 8];
      bf16x8 kf1 = *(const bf16x8*)&Ks[cf * 16 + r][32 + g * 8];
      f32x4 t = (f32x4){0.f, 0.f, 0.f, 0.f};
      t = MFMA_16x16x32(qf0, kf0, t);
      t = MFMA_16x16x32(qf1, kf1, t);
      s[cf] = t;
    }

    const bool diag = (kv == qt);
    float pm[4] = {-1e30f, -1e30f, -1e30f, -1e30f};
    #pragma unroll
    for (int cf = 0; cf < 4; cf++) {
      #pragma unroll
      for (int j = 0; j < 4; j++) {
        float v = s[cf][j] * scale;
        if (diag && (cf * 16 + r) > (w * 16 + g * 4 + j)) v = -1e30f;
        s[cf][j] = v;
        pm[j] = fmaxf(pm[j], v);
      }
    }
    #pragma unroll
    for (int j = 0; j < 4; j++) {
      #pragma unroll
      for (int msk = 1; msk < 16; msk <<= 1)
        pm[j] = fmaxf(pm[j], __shfl_xor(pm[j], msk, 64));
    }
    float corr[4];
    #pragma unroll
    for (int j = 0; j < 4; j++) {
      float mn = fmaxf(m_r[j], pm[j]);
      corr[j] = __expf(m_r[j] - mn);
      m_r[j] = mn;
    }
    float rs[4] = {0.f, 0.f, 0.f, 0.f};
    #pragma unroll
    for (int cf = 0; cf < 4; cf++) {
      #pragma unroll
      for (int j = 0; j < 4; j++) {
        float pv = __expf(s[cf][j] - m_r[j]);
        s[cf][j] = pv;
        rs[j] += pv;
      }
    }
    #pragma unroll
    for (int j = 0; j < 4; j++) {
      #pragma unroll
      for (int msk = 1; msk < 16; msk <<= 1)
        rs[j] += __shfl_xor(rs[j], msk, 64);
      l_r[j] = l_r[j] * corr[j] + rs[j];
    }
    #pragma unroll
    for (int hf = 0; hf < 4; hf++)
      #pragma unroll
      for (int j = 0; j < 4; j++)
        acc_o[hf][j] *= corr[j];

    #pragma unroll
    for (int cf = 0; cf < 4; cf++)
      #pragma unroll
      for (int j = 0; j < 4; j++)
        Ps[w][g * 4 + j][cf * 16 + r] = (bf16)s[cf][j];

    __syncthreads();

    #pragma unroll
    for (int ss = 0; ss < 2; ss++) {
      bf16x8 pf = *(const bf16x8*)&Ps[w][r][ss * 32 + g * 8];
      #pragma unroll
      for (int hf = 0; hf < 4; hf++) {
        bf16x8 vf = *(const bf16x8*)&Vs[hf * 16 + r][ss * 32 + g * 8];
        acc_o[hf] = MFMA_16x16x32(pf, vf, acc_o[hf]);
      }
    }
    __syncthreads();
  }

  float inv[4];
  #pragma unroll
  for (int j = 0; j < 4; j++) inv[j] = 1.0f / l_r[j];
  const size_t ob = (size_t)(b * 2048 + q0) * 64;
  #pragma unroll
  for (int hf = 0; hf < 4; hf++)
    #pragma unroll
    for (int j = 0; j < 4; j++)
      out[ob + (size_t)(g * 4 + j) * 64 + hf * 16 + r] = acc_o[hf][j] * inv[j];
}

// ---------------------------------------------------------------------------
extern "C" void kernel_launch(void* const* d_in, const int* in_sizes, int n_in,
                              void* d_out, int out_size, void* d_ws, size_t ws_size,
                              hipStream_t stream)
{
  const float* q  = (const float*)d_in[0];
  const float* k  = (const float*)d_in[1];
  const float* Wq = (const float*)d_in[2];
  const float* Wk = (const float*)d_in[3];
  const float* Wv = (const float*)d_in[4];
  float* out = (float*)d_out;

  char* ws = (char*)d_ws;
  bf16* Qb  = (bf16*)(ws);                      // [16*2048][64] bf16, 4MB
  bf16* Kb  = (bf16*)(ws + (4u << 20));         // [16*2048][64] bf16, 4MB
  bf16* Vtb = (bf16*)(ws + (8u << 20));         // [16][64][2048] bf16, 4MB
  bf16* Wt  = (bf16*)(ws + (12u << 20));        // [3][64][1024] bf16, 384KB

  hipLaunchKernelGGL(wtrans_kernel, dim3(768), dim3(256), 0, stream,
                     Wq, Wk, Wv, Wt);
  hipLaunchKernelGGL(proj_kernel, dim3(512), dim3(256), 0, stream,
                     q, k, Wt, Qb, Kb, Vtb);
  hipLaunchKernelGGL(attn_kernel, dim3(32, 16), dim3(256), 0, stream,
                     Qb, Kb, Vtb, out);
}